// Round 6
// baseline (149.353 us; speedup 1.0000x reference)
//
#include <hip/hip_runtime.h>

// out = conv2d(poly(img), W, stride=1, pad=1) / 27, poly(v) = A0 + A1*v + A2*v^2
// (identity-kernel branch contributes exactly zero; 1/27 folded into poly).
//
// R6: two-kernel, barrier-free structure.
//  k1 poly_pack: img fp32 -> padded bf16 image pimg[n][cc8][yp 130][xp 130][cj 8]
//     (zero pad ring = conv zero-padding; pure streaming kernel).
//  k2 conv_mfma: one wave per 64o x 32x output tile; B-frags are direct global
//     dwordx4 loads from pimg (no LDS, no __syncthreads); A-frags from repacked
//     weights. 36 unrolled k-steps of mfma_f32_32x32x16_bf16.

typedef __bf16 bf16;
typedef __attribute__((ext_vector_type(8))) __bf16 bf16x8;
typedef __attribute__((ext_vector_type(16))) float f32x16;

static constexpr float A0 = -0.000287f / 27.0f;
static constexpr float A1 =  0.266f    / 27.0f;
static constexpr float A2 = -0.1097f   / 27.0f;

#define NN 16
#define CI 64
#define HH 128
#define WW 128
#define OO 64
#define HW (HH * WW)
#define PW 130                 // padded spatial extent
#define PPLANE (PW * PW)       // bf16x8 elements per (n,cc8) plane

// ---- k1: poly + pack + pad. Interior: 2^21 threads (one bf16x8 each).
//      Pad ring: 128 planes * 516 positions = 66048 zero writes.
__global__ __launch_bounds__(256) void poly_pack(const float* __restrict__ img,
                                                 bf16x8* __restrict__ pimg) {
    const int t = blockIdx.x * 256 + threadIdx.x;
    if (t < (1 << 21)) {
        const int x   = t & 127;
        const int y   = (t >> 7) & 127;
        const int cc8 = (t >> 14) & 7;
        const int n   = t >> 17;
        const float* p = img + ((n * CI + cc8 * 8) * HH + y) * WW + x;
        bf16x8 pk;
        #pragma unroll
        for (int j = 0; j < 8; ++j) {
            float v = p[j * HW];                       // coalesced across lanes (x)
            pk[j] = (bf16)(A0 + v * (A1 + A2 * v));
        }
        pimg[(n * 8 + cc8) * PPLANE + (y + 1) * PW + (x + 1)] = pk;
    } else {
        int p = t - (1 << 21);                         // [0, 66048)
        const int nc = p / 516;                        // plane index [0,128)
        int pi = p - nc * 516;
        int yp, xp;
        if (pi < 260) {                                // top/bottom rows, full width
            yp = (pi < 130) ? 0 : 129;
            xp = (pi < 130) ? pi : pi - 130;
        } else {                                       // left/right columns
            int q = pi - 260;                          // [0,256)
            xp = (q < 128) ? 0 : 129;
            yp = ((q < 128) ? q : q - 128) + 1;        // [1,128]
        }
        bf16x8 z;
        #pragma unroll
        for (int j = 0; j < 8; ++j) z[j] = (bf16)0.0f;
        pimg[nc * PPLANE + yp * PW + xp] = z;
    }
}

// ---- Repack weights [O][C][3][3] fp32 -> [slice=ky*3+kx][cc8][o][cj] bf16.
__global__ void repack_w(const float* __restrict__ w, bf16* __restrict__ wrb) {
    int idx = blockIdx.x * 256 + threadIdx.x;          // 9*8*64*8 = 36864
    if (idx >= 9 * 8 * 64 * 8) return;
    int cj    = idx & 7;
    int o     = (idx >> 3) & 63;
    int cc8   = (idx >> 9) & 7;
    int slice = idx >> 12;
    int ky = slice / 3, kx = slice - ky * 3;
    int c = cc8 * 8 + cj;
    wrb[idx] = (bf16)w[((o * CI + c) * 3 + ky) * 3 + kx];
}

// ---- k2: barrier-free conv. Block = 256 thr = 4 waves; wave wv owns x-quarter
//      x0 = wv*32 of row (n, y). XCD swizzle: each XCD gets a contiguous
//      16-row y-band so ky-halo re-reads stay in its own L2.
__global__ __launch_bounds__(256, 4) void conv_mfma(const bf16x8* __restrict__ pimg,
                                                    const bf16x8* __restrict__ wfr,
                                                    float* __restrict__ out) {
    const int g   = blockIdx.x;
    const int xcd = g & 7;
    const int idx = g >> 3;
    const int y   = xcd * 16 + (idx & 15);
    const int n   = idx >> 4;

    const int tid  = threadIdx.x;
    const int wv   = tid >> 6;
    const int lane = tid & 63;
    const int lm   = lane & 31;      // A: o-row / B: x-col / C: col
    const int half = lane >> 5;      // k-half: which cc8 of the pair
    const int x0   = wv * 32;

    // Per-lane B base: pimg plane (n*8 + half), padded row y (=img row y-1+... via +ky),
    // padded col x0+lm (+kx). All 16B-aligned, lane-contiguous 512B segments.
    const bf16x8* vb = pimg + ((n * 8 + half) * PPLANE + y * PW + x0 + lm);

    f32x16 acc0, acc1;
    #pragma unroll
    for (int k = 0; k < 16; ++k) { acc0[k] = 0.0f; acc1[k] = 0.0f; }

    #pragma unroll
    for (int ky = 0; ky < 3; ++ky) {
        #pragma unroll
        for (int kx = 0; kx < 3; ++kx) {
            const int slice = ky * 3 + kx;
            #pragma unroll
            for (int ccp = 0; ccp < 4; ++ccp) {
                // B: image fragment, direct from global (L1/L2/L3-served).
                bf16x8 b = vb[(ccp * 2) * PPLANE + ky * PW + kx];
                // A: weight fragments (o = lm and o = 32+lm), cache-hot.
                bf16x8 a0 = wfr[(slice * 8 + ccp * 2 + half) * 64 + lm];
                bf16x8 a1 = wfr[(slice * 8 + ccp * 2 + half) * 64 + 32 + lm];
                acc0 = __builtin_amdgcn_mfma_f32_32x32x16_bf16(a0, b, acc0, 0, 0, 0);
                acc1 = __builtin_amdgcn_mfma_f32_32x32x16_bf16(a1, b, acc1, 0, 0, 0);
            }
        }
    }

    // Epilogue: C/D layout col = lane&31 (x), o-in-32 = (rg&3) + 8*(rg>>2) + 4*half.
    // Each store: two 128B lane-contiguous segments.
    float* op = out + (n * OO * HH + y) * WW + x0 + lm;
    #pragma unroll
    for (int rg = 0; rg < 16; ++rg) {
        const int o = (rg & 3) + 8 * (rg >> 2) + 4 * half;
        op[o * HW]        = acc0[rg];
        op[(o + 32) * HW] = acc1[rg];
    }
}

extern "C" void kernel_launch(void* const* d_in, const int* in_sizes, int n_in,
                              void* d_out, int out_size, void* d_ws, size_t ws_size,
                              hipStream_t stream) {
    const float* img = (const float*)d_in[0];
    const float* w   = (const float*)d_in[1];
    // d_in[2] (identity_kernel) unused: its branch convolves exact zeros.
    float* out = (float*)d_out;

    // ws layout: [pimg: 16*8*130*130*8 bf16 = 34,611,200 B][wrb: 73,728 B]
    bf16x8* pimg = (bf16x8*)d_ws;
    bf16*   wrb  = (bf16*)((char*)d_ws + (size_t)NN * 8 * PPLANE * 16);

    poly_pack<<<8450, 256, 0, stream>>>(img, pimg);                    // 2163200 threads
    repack_w<<<(9 * 8 * 64 * 8 + 255) / 256, 256, 0, stream>>>(w, wrb);
    conv_mfma<<<NN * HH, 256, 0, stream>>>(pimg, (const bf16x8*)wrb, out);
}